// Round 2
// baseline (422.364 us; speedup 1.0000x reference)
//
#include <hip/hip_runtime.h>

#define B_ 1024
#define N_ 24
#define CI_ 2
#define CO_ 2
#define E_ 256
#define H_ 4
#define DH_ 64

typedef __bf16 v8bf __attribute__((ext_vector_type(8)));
typedef float v4f __attribute__((ext_vector_type(4)));

union Frag {
    uint4 u;
    v8bf v;
};

__device__ __forceinline__ v4f mfma16(v8bf a, v8bf b, v4f c) {
    return __builtin_amdgcn_mfma_f32_16x16x32_bf16(a, b, c, 0, 0, 0);
}

// load 8 consecutive f32 and round to 8 bf16 (for MFMA A/B fragments)
__device__ __forceinline__ v8bf cvt8(const float* __restrict__ p) {
    float4 a = *(const float4*)p;
    float4 b = *(const float4*)(p + 4);
    v8bf r;
    r[0] = (__bf16)a.x; r[1] = (__bf16)a.y; r[2] = (__bf16)a.z; r[3] = (__bf16)a.w;
    r[4] = (__bf16)b.x; r[5] = (__bf16)b.y; r[6] = (__bf16)b.z; r[7] = (__bf16)b.w;
    return r;
}

// ---------------------------------------------------------------------------
// Kernel T: downcast f32->bf16 + transpose last-two-dims of kernel tensor
// (96 mats of 256x256) and Wq/Wk/Wv (3 mats) so MFMA B-fragments become
// contiguous 16B bf16 loads.
// ---------------------------------------------------------------------------
__global__ __launch_bounds__(256) void ktrans(
    const float* __restrict__ kern, const float* __restrict__ wq,
    const float* __restrict__ wk, const float* __restrict__ wv,
    __bf16* __restrict__ wt, __bf16* __restrict__ kt) {
    __shared__ __bf16 t[64][65];
    const int blk = blockIdx.x;
    const int mat = blk >> 4, tile = blk & 15;
    const int r0 = (tile >> 2) * 64, c0 = (tile & 3) * 64;
    const float* src;
    __bf16* dst;
    if (mat < 96) {
        src = kern + (size_t)mat * 65536;
        dst = kt + (size_t)mat * 65536;
    } else {
        int p = mat - 96;
        src = (p == 0) ? wq : (p == 1) ? wk : wv;
        dst = wt + (size_t)p * 65536;
    }
    const int tid = threadIdx.x;
#pragma unroll
    for (int k = 0; k < 16; ++k) {
        int idx = k * 256 + tid;
        int e = idx >> 6, f = idx & 63;
        t[f][e] = (__bf16)src[(size_t)(r0 + e) * 256 + c0 + f];
    }
    __syncthreads();
#pragma unroll
    for (int k = 0; k < 16; ++k) {
        int idx = k * 256 + tid;
        int f = idx >> 6, e = idx & 63;
        dst[(size_t)(c0 + f) * 256 + r0 + e] = t[f][e];
    }
}

// ---------------------------------------------------------------------------
// Kernel A: per-b fused attention. 512 threads = 8 waves.
// Phase 1: QKV = x@W + b via MFMA (2 seqs * 32 padded rows = 4 row-frags;
//          each wave owns 2 col-frags of 16). Store Q,K (bf16) and V^T to LDS.
// Phase 2: scores = QK^T/8 via MFMA per (seq,head)=wave; softmax in-register
//          with 16-lane shuffles; P -> LDS (kn pads zeroed).
// Phase 3: ctx = P@V via MFMA; store bf16 ctx[b][i][n][f] to ws.
// ---------------------------------------------------------------------------
__global__ __launch_bounds__(512) void kattn(
    const float* __restrict__ feat, const __bf16* __restrict__ wt,
    const float* __restrict__ bq, const float* __restrict__ bk,
    const float* __restrict__ bv, __bf16* __restrict__ ctx) {
    __shared__ __bf16 sQ[CI_][N_][E_];     // 24 KB
    __shared__ __bf16 sK[CI_][N_][E_];     // 24 KB
    __shared__ __bf16 sVT[CI_][E_][N_];    // 24 KB  (V transposed: [f][kn])
    __shared__ __bf16 sP[CI_][H_][N_][32]; // 12 KB  (probs, kn padded to 32)

    const int b = blockIdx.x;
    const int tid = threadIdx.x;
    const int wave = tid >> 6, lane = tid & 63;
    const int quad = lane >> 4, l16 = lane & 15;
    const float* pb[3] = {bq, bk, bv};

    const uint4 zero4 = make_uint4(0u, 0u, 0u, 0u);
    const v4f zf = {0.f, 0.f, 0.f, 0.f};

    // ---------------- Phase 1: QKV projections ----------------
#pragma unroll
    for (int p = 0; p < 3; ++p) {
        const __bf16* W = wt + (size_t)p * 65536;
        v4f acc[4][2];
#pragma unroll
        for (int rf = 0; rf < 4; ++rf)
#pragma unroll
            for (int c = 0; c < 2; ++c) acc[rf][c] = zf;

#pragma unroll
        for (int ks = 0; ks < 8; ++ks) {
            const int kb = ks * 32 + quad * 8;
            Frag a[4], bb[2];
#pragma unroll
            for (int rf = 0; rf < 4; ++rf) {
                const int n = (rf & 1) * 16 + l16;
                const int i = rf >> 1;
                if (n < N_)
                    a[rf].v = cvt8(feat + ((size_t)((b * N_ + n) * CI_ + i)) * E_ + kb);
                else
                    a[rf].u = zero4;
            }
#pragma unroll
            for (int c = 0; c < 2; ++c) {
                const int f0 = (wave * 2 + c) * 16;
                bb[c].u = *(const uint4*)(W + (size_t)(f0 + l16) * E_ + kb);
            }
#pragma unroll
            for (int rf = 0; rf < 4; ++rf)
#pragma unroll
                for (int c = 0; c < 2; ++c)
                    acc[rf][c] = mfma16(a[rf].v, bb[c].v, acc[rf][c]);
        }
        // store to LDS (+bias)
#pragma unroll
        for (int c = 0; c < 2; ++c) {
            const int f = (wave * 2 + c) * 16 + l16;
            const float biasf = pb[p][f];
#pragma unroll
            for (int rf = 0; rf < 4; ++rf) {
#pragma unroll
                for (int r = 0; r < 4; ++r) {
                    const int row = rf * 16 + quad * 4 + r;
                    const int i = row >> 5, np = row & 31;
                    if (np < N_) {
                        const float v = acc[rf][c][r] + biasf;
                        if (p == 0) sQ[i][np][f] = (__bf16)v;
                        else if (p == 1) sK[i][np][f] = (__bf16)v;
                        else sVT[i][f][np] = (__bf16)v;
                    }
                }
            }
        }
    }
    __syncthreads();

    // ---------------- Phase 2: scores + softmax (one (seq,h) per wave) -----
    const int seq = wave >> 2, h = wave & 3;
    v4f sc[2][2];
#pragma unroll
    for (int mt = 0; mt < 2; ++mt)
#pragma unroll
        for (int nt = 0; nt < 2; ++nt) sc[mt][nt] = zf;

#pragma unroll
    for (int ks = 0; ks < 2; ++ks) {
        const int d0 = h * DH_ + ks * 32 + quad * 8;
        Frag a[2], bb[2];
#pragma unroll
        for (int mt = 0; mt < 2; ++mt) {
            const int qn = mt * 16 + l16;
            a[mt].u = (qn < N_) ? *(const uint4*)(&sQ[seq][qn][d0]) : zero4;
        }
#pragma unroll
        for (int nt = 0; nt < 2; ++nt) {
            const int kn = nt * 16 + l16;
            bb[nt].u = (kn < N_) ? *(const uint4*)(&sK[seq][kn][d0]) : zero4;
        }
#pragma unroll
        for (int mt = 0; mt < 2; ++mt)
#pragma unroll
            for (int nt = 0; nt < 2; ++nt)
                sc[mt][nt] = mfma16(a[mt].v, bb[nt].v, sc[mt][nt]);
    }

    const float scale = 0.125f;  // 1/sqrt(64)
#pragma unroll
    for (int mt = 0; mt < 2; ++mt) {
#pragma unroll
        for (int r = 0; r < 4; ++r) {
            const int qn = mt * 16 + quad * 4 + r;
            const float v0 = sc[mt][0][r] * scale;
            const float v1 = (l16 < 8) ? sc[mt][1][r] * scale : -3.0e38f;  // kn=16+l16 >= 24 masked
            float mx = fmaxf(v0, v1);
#pragma unroll
            for (int m = 1; m < 16; m <<= 1) mx = fmaxf(mx, __shfl_xor(mx, m));
            const float e0 = __expf(v0 - mx);
            const float e1 = (l16 < 8) ? __expf(v1 - mx) : 0.f;
            float s = e0 + e1;
#pragma unroll
            for (int m = 1; m < 16; m <<= 1) s += __shfl_xor(s, m);
            const float inv = 1.f / s;
            if (qn < N_) {
                sP[seq][h][qn][l16] = (__bf16)(e0 * inv);
                sP[seq][h][qn][16 + l16] = (__bf16)(e1 * inv);
            }
        }
    }
    __syncthreads();  // safety: order sP writes before Phase-3 reads

    // ---------------- Phase 3: ctx = P @ V ----------------
    Frag pa[2], vb[4];
#pragma unroll
    for (int mt = 0; mt < 2; ++mt) {
        const int qn = mt * 16 + l16;
        pa[mt].u = (qn < N_) ? *(const uint4*)(&sP[seq][h][qn][quad * 8]) : zero4;
    }
#pragma unroll
    for (int nt = 0; nt < 4; ++nt) {
        // kn = quad*8 + j ; quad==3 -> kn in [24,32) : zero (P there is 0 anyway)
        vb[nt].u = (quad < 3) ? *(const uint4*)(&sVT[seq][h * DH_ + nt * 16 + l16][quad * 8]) : zero4;
    }
#pragma unroll
    for (int mt = 0; mt < 2; ++mt) {
#pragma unroll
        for (int nt = 0; nt < 4; ++nt) {
            v4f c0 = zf;
            c0 = mfma16(pa[mt].v, vb[nt].v, c0);
#pragma unroll
            for (int r = 0; r < 4; ++r) {
                const int qn = mt * 16 + quad * 4 + r;
                if (qn < N_) {
                    const int f = h * DH_ + nt * 16 + l16;
                    ctx[((size_t)((b * CI_ + seq) * N_ + qn)) * E_ + f] = (__bf16)c0[r];
                }
            }
        }
    }
}

// ---------------------------------------------------------------------------
// Kernel P: pkq[b,n,o,f] = sum_i ctx[b,i,n,f] * (feat[b,n,i,:] @ K[o,i,n,:,f])
//           + bias + residual, then LayerNorm over f.
// Grid (16, 24, 2): 64 b-rows x 256 f-cols per block; wave w owns rows
// [16w,16w+16). K-contraction E=256 via MFMA; per-i result scaled by ctx.
// ---------------------------------------------------------------------------
__global__ __launch_bounds__(256) void kpkln(
    const float* __restrict__ feat, const __bf16* __restrict__ kt,
    const __bf16* __restrict__ ctx, const float* __restrict__ bias,
    const float* __restrict__ gamma, const float* __restrict__ beta,
    float* __restrict__ out) {
    const int bt = blockIdx.x;  // 0..15
    const int n = blockIdx.y;   // 0..23
    const int o = blockIdx.z;   // 0..1
    const int tid = threadIdx.x;
    const int wave = tid >> 6, lane = tid & 63;
    const int quad = lane >> 4, l16 = lane & 15;
    const int b0 = bt * 64 + wave * 16;

    const v4f zf = {0.f, 0.f, 0.f, 0.f};
    float accf[16][4];
#pragma unroll
    for (int cf = 0; cf < 16; ++cf)
#pragma unroll
        for (int r = 0; r < 4; ++r) accf[cf][r] = 0.f;

#pragma unroll
    for (int i = 0; i < CI_; ++i) {
        v4f g[16];
#pragma unroll
        for (int cf = 0; cf < 16; ++cf) g[cf] = zf;

        const float* A = feat + ((size_t)((b0 + l16) * N_ + n) * CI_ + i) * E_;
        const __bf16* Bm = kt + ((size_t)((o * CI_ + i) * N_ + n)) * 65536;
#pragma unroll
        for (int ks = 0; ks < 8; ++ks) {
            const int kb = ks * 32 + quad * 8;
            Frag a;
            a.v = cvt8(A + kb);
#pragma unroll
            for (int cf = 0; cf < 16; ++cf) {
                Frag bb;
                bb.u = *(const uint4*)(Bm + (size_t)(cf * 16 + l16) * E_ + kb);
                g[cf] = mfma16(a.v, bb.v, g[cf]);
            }
        }
        // scale by ctx and accumulate over i
#pragma unroll
        for (int cf = 0; cf < 16; ++cf) {
            const int f = cf * 16 + l16;
#pragma unroll
            for (int r = 0; r < 4; ++r) {
                const int brow = b0 + quad * 4 + r;
                const float cv = (float)ctx[((size_t)((brow * CI_ + i) * N_ + n)) * E_ + f];
                accf[cf][r] += cv * g[cf][r];
            }
        }
    }

    // epilogue: +bias +residual, LayerNorm over f (256), store f32
    const float bias_no = bias[n * CO_ + o];
#pragma unroll
    for (int r = 0; r < 4; ++r) {
        const int brow = b0 + quad * 4 + r;
        const float* resid = feat + ((size_t)((brow * N_ + n) * CI_ + o)) * E_;
        float s = 0.f;
#pragma unroll
        for (int cf = 0; cf < 16; ++cf) {
            const float v = accf[cf][r] + bias_no + resid[cf * 16 + l16];
            accf[cf][r] = v;
            s += v;
        }
#pragma unroll
        for (int m = 1; m < 16; m <<= 1) s += __shfl_xor(s, m);
        const float mean = s * (1.f / 256.f);
        float s2 = 0.f;
#pragma unroll
        for (int cf = 0; cf < 16; ++cf) {
            const float d = accf[cf][r] - mean;
            s2 += d * d;
        }
#pragma unroll
        for (int m = 1; m < 16; m <<= 1) s2 += __shfl_xor(s2, m);
        const float rstd = rsqrtf(s2 * (1.f / 256.f) + 1e-12f);
        float* op = out + ((size_t)((brow * N_ + n) * CO_ + o)) * E_;
#pragma unroll
        for (int cf = 0; cf < 16; ++cf) {
            const int f = cf * 16 + l16;
            op[f] = (accf[cf][r] - mean) * rstd * gamma[f] + beta[f];
        }
    }
}

// ---------------------------------------------------------------------------
extern "C" void kernel_launch(void* const* d_in, const int* in_sizes, int n_in,
                              void* d_out, int out_size, void* d_ws, size_t ws_size,
                              hipStream_t stream) {
    const float* feat = (const float*)d_in[0];
    const float* kern = (const float*)d_in[1];
    const float* bias = (const float*)d_in[2];
    const float* wq = (const float*)d_in[3];
    const float* bq = (const float*)d_in[4];
    const float* wk = (const float*)d_in[5];
    const float* bk = (const float*)d_in[6];
    const float* wv = (const float*)d_in[7];
    const float* bv = (const float*)d_in[8];
    const float* gamma = (const float*)d_in[9];
    const float* beta = (const float*)d_in[10];

    __bf16* ws = (__bf16*)d_ws;
    __bf16* wt = ws;                        // 3 * 65536 bf16
    __bf16* kt = ws + (size_t)3 * 65536;    // 96 * 65536 bf16
    __bf16* ctx = kt + (size_t)96 * 65536;  // 2048 * 24 * 256 bf16
    float* out = (float*)d_out;

    hipLaunchKernelGGL(ktrans, dim3(99 * 16), dim3(256), 0, stream,
                       kern, wq, wk, wv, wt, kt);
    hipLaunchKernelGGL(kattn, dim3(B_), dim3(512), 0, stream,
                       feat, wt, bq, bk, bv, ctx);
    hipLaunchKernelGGL(kpkln, dim3(16, N_, CO_), dim3(256), 0, stream,
                       feat, kt, ctx, bias, gamma, beta, out);
}